// Round 1
// baseline (51.973 us; speedup 1.0000x reference)
//
#include <hip/hip_runtime.h>

#define MDIM 256
#define BATCH 256
#define DIMINISH 0.5f

// Kernel 1: one block per (batch, row i). Skips rows with i >= doc_len[b]
// entirely (no global reads of y_true/y_pred). Each thread handles one pair
// (j column): 8B int2 from y_true + 8B float2 from y_pred, coalesced.
__global__ __launch_bounds__(256) void row_loss_kernel(
    const int*   __restrict__ y_true,
    const float* __restrict__ y_pred,
    const int*   __restrict__ doc_len,
    float*       __restrict__ partial)
{
    const int blk = blockIdx.x;
    const int b = blk >> 8;     // / 256
    const int i = blk & 255;    // % 256
    const int dl = doc_len[b];

    float sum = 0.0f;
    if (i < dl) {
        const int j = threadIdx.x;
        if (j < dl) {
            const size_t base = (((size_t)b * (MDIM * MDIM)) + (size_t)i * MDIM + j) * 2;
            const int2   yt = *reinterpret_cast<const int2*>(y_true + base);
            const float2 yp = *reinterpret_cast<const float2*>(y_pred + base);
            float c = 0.0f;
            if (yt.y == 1) c -= __logf(yp.y);          // pos term
            if (yt.x == 1) c -= DIMINISH * __logf(yp.x); // neg term (×0.5)
            sum = c;
        }
    } else {
        // whole row invalid: write zero partial and leave (no data reads)
        if (threadIdx.x == 0) partial[blk] = 0.0f;
        return;
    }

    // wave (64-lane) shuffle reduction
    #pragma unroll
    for (int off = 32; off > 0; off >>= 1)
        sum += __shfl_down(sum, off, 64);

    __shared__ float wsum[4];
    const int lane = threadIdx.x & 63;
    const int wid  = threadIdx.x >> 6;
    if (lane == 0) wsum[wid] = sum;
    __syncthreads();
    if (threadIdx.x == 0)
        partial[blk] = wsum[0] + wsum[1] + wsum[2] + wsum[3];
}

// Kernel 2: deterministic reduction of 65536 partials + doc_len sum, writes
// the single scalar output (always overwrites d_out -> no stale-state issues).
__global__ __launch_bounds__(1024) void final_reduce_kernel(
    const float* __restrict__ partial,
    const int*   __restrict__ doc_len,
    float*       __restrict__ out)
{
    float s = 0.0f;
    for (int idx = threadIdx.x; idx < BATCH * MDIM; idx += 1024)
        s += partial[idx];

    #pragma unroll
    for (int off = 32; off > 0; off >>= 1)
        s += __shfl_down(s, off, 64);

    __shared__ float wsum[16];
    const int lane = threadIdx.x & 63;
    const int wid  = threadIdx.x >> 6;
    if (lane == 0) wsum[wid] = s;
    __syncthreads();

    if (threadIdx.x < 64) {
        float v = (threadIdx.x < 16) ? wsum[threadIdx.x] : 0.0f;
        #pragma unroll
        for (int off = 8; off > 0; off >>= 1)
            v += __shfl_down(v, off, 64);
        if (threadIdx.x == 0) {
            int dls = 0;
            for (int bb = 0; bb < BATCH; ++bb) dls += doc_len[bb];
            out[0] = v / (float)dls;
        }
    }
}

extern "C" void kernel_launch(void* const* d_in, const int* in_sizes, int n_in,
                              void* d_out, int out_size, void* d_ws, size_t ws_size,
                              hipStream_t stream)
{
    const int*   y_true  = (const int*)d_in[0];   // (B, M*M, 2) int32
    const float* y_pred  = (const float*)d_in[1]; // (B, M*M, 2) float32
    const int*   doc_len = (const int*)d_in[2];   // (B,) int32
    float*       out     = (float*)d_out;
    float*       partial = (float*)d_ws;          // 65536 floats = 256 KB

    row_loss_kernel<<<BATCH * MDIM, 256, 0, stream>>>(y_true, y_pred, doc_len, partial);
    final_reduce_kernel<<<1, 1024, 0, stream>>>(partial, doc_len, out);
}

// Round 2
// 26.896 us; speedup vs baseline: 1.9324x; 1.9324x over previous
//
#include <hip/hip_runtime.h>

#define MDIM 256
#define BATCH 256
#define DIMINISH 0.5f
#define ROWS_PER_BLOCK 16
#define BLOCKS_PER_BATCH (MDIM / ROWS_PER_BLOCK)   // 16
#define NBLOCKS (BATCH * BLOCKS_PER_BATCH)          // 4096

// Kernel 1: one 256-thread block per (batch, 16-row slab). Waves (4) own
// interleaved rows; each lane loads 2 pairs via int4 + float4 (16B/lane).
// Column chunks beyond doc_len are never loaded (traffic ~ sum(dl^2)).
__global__ __launch_bounds__(256) void row_loss_kernel(
    const int*   __restrict__ y_true,
    const float* __restrict__ y_pred,
    const int*   __restrict__ doc_len,
    float*       __restrict__ partial)
{
    const int blk  = blockIdx.x;
    const int b    = blk >> 4;            // / BLOCKS_PER_BATCH
    const int r0   = (blk & 15) * ROWS_PER_BLOCK;
    const int dl   = doc_len[b];

    if (r0 >= dl) {                        // whole slab invalid: no data reads
        if (threadIdx.x == 0) partial[blk] = 0.0f;
        return;
    }

    const int lane = threadIdx.x & 63;
    const int wid  = threadIdx.x >> 6;

    float sum = 0.0f;
    // wave w handles rows r0+w, r0+w+4, r0+w+8, r0+w+12
    for (int r = r0 + wid; r < r0 + ROWS_PER_BLOCK; r += 4) {
        if (r >= dl) continue;
        const size_t rowbase = ((size_t)b * (MDIM * MDIM)) + (size_t)r * MDIM;
        #pragma unroll
        for (int c = 0; c < 2; ++c) {
            const int j = c * 128 + lane * 2;      // pair index (2 pairs/lane)
            if (j >= dl) continue;
            const size_t e = (rowbase + (size_t)j) * 2;   // element offset
            const int4   yt = *reinterpret_cast<const int4*>(y_true + e);
            const float4 yp = *reinterpret_cast<const float4*>(y_pred + e);
            // pair j   : flags yt.x (neg), yt.y (pos); preds yp.x, yp.y
            sum -= (float)yt.y * __logf(yp.y) + DIMINISH * (float)yt.x * __logf(yp.x);
            // pair j+1 : flags yt.z, yt.w; preds yp.z, yp.w
            if (j + 1 < dl)
                sum -= (float)yt.w * __logf(yp.w) + DIMINISH * (float)yt.z * __logf(yp.z);
        }
    }

    // wave shuffle reduction
    #pragma unroll
    for (int off = 32; off > 0; off >>= 1)
        sum += __shfl_down(sum, off, 64);

    __shared__ float wsum[4];
    if (lane == 0) wsum[wid] = sum;
    __syncthreads();
    if (threadIdx.x == 0)
        partial[blk] = wsum[0] + wsum[1] + wsum[2] + wsum[3];
}

// Kernel 2: deterministic reduction of 4096 partials + doc_len sum.
__global__ __launch_bounds__(1024) void final_reduce_kernel(
    const float* __restrict__ partial,
    const int*   __restrict__ doc_len,
    float*       __restrict__ out)
{
    const int t    = threadIdx.x;
    const int lane = t & 63;
    const int wid  = t >> 6;

    float s = 0.0f;
    #pragma unroll
    for (int k = 0; k < NBLOCKS / 1024; ++k)
        s += partial[t + k * 1024];

    float d = (t < BATCH) ? (float)doc_len[t] : 0.0f;

    #pragma unroll
    for (int off = 32; off > 0; off >>= 1) {
        s += __shfl_down(s, off, 64);
        d += __shfl_down(d, off, 64);
    }

    __shared__ float wsum[16], wdl[16];
    if (lane == 0) { wsum[wid] = s; wdl[wid] = d; }
    __syncthreads();

    if (t < 64) {
        float v  = (t < 16) ? wsum[t] : 0.0f;
        float dv = (t < 16) ? wdl[t]  : 0.0f;
        #pragma unroll
        for (int off = 8; off > 0; off >>= 1) {
            v  += __shfl_down(v, off, 64);
            dv += __shfl_down(dv, off, 64);
        }
        if (t == 0) out[0] = v / dv;
    }
}

extern "C" void kernel_launch(void* const* d_in, const int* in_sizes, int n_in,
                              void* d_out, int out_size, void* d_ws, size_t ws_size,
                              hipStream_t stream)
{
    const int*   y_true  = (const int*)d_in[0];   // (B, M*M, 2) int32
    const float* y_pred  = (const float*)d_in[1]; // (B, M*M, 2) float32
    const int*   doc_len = (const int*)d_in[2];   // (B,) int32
    float*       out     = (float*)d_out;
    float*       partial = (float*)d_ws;          // 4096 floats = 16 KB

    row_loss_kernel<<<NBLOCKS, 256, 0, stream>>>(y_true, y_pred, doc_len, partial);
    final_reduce_kernel<<<1, 1024, 0, stream>>>(partial, doc_len, out);
}